// Round 1
// baseline (285.487 us; speedup 1.0000x reference)
//
#include <hip/hip_runtime.h>

typedef _Float16 f16;
typedef _Float16 f16x8 __attribute__((ext_vector_type(8)));
typedef _Float16 f16x4 __attribute__((ext_vector_type(4)));
typedef _Float16 f16x2 __attribute__((ext_vector_type(2)));
typedef float f32x16 __attribute__((ext_vector_type(16)));
typedef float f32x4 __attribute__((ext_vector_type(4)));
typedef unsigned int u32;
typedef u32 u32x4 __attribute__((ext_vector_type(4)));

#define MFMA_F16 __builtin_amdgcn_mfma_f32_32x32x16_f16

// Problem constants: x is (B=8, N=4096, C=64) fp32; out = gamma*softmax(qq^T)q + x
constexpr int N  = 4096;
constexpr int C  = 64;
constexpr int KV = 64;        // keys per tile
constexpr int QB = 128;       // queries per block (4 waves x 32)
constexpr int NT = N / KV;    // 64 KV tiles

// XOR swizzle for [rows][64] f16 tiles (128 B rows): spreads the 128-B-stride
// row reads across banks (T2).  bcol in bytes [0,128).
__device__ __forceinline__ int swz(int row, int bcol) {
    return row * 128 + (bcol ^ ((row & 7) << 4));
}

__global__ __launch_bounds__(256, 1)
void channel_attn_kernel(const float* __restrict__ x,
                         const float* __restrict__ gamma,
                         float* __restrict__ out) {
    // LDS: staging = 2x K[64][64]f16 (16 KB) + 2x V^T[64][64]f16 (16 KB) = 32 KB
    // epilogue reuse: 4 waves x [64][33] f32 = 33792 B  (max -> 33792)
    __shared__ __align__(16) unsigned char smem[33792];

    const int tid = threadIdx.x;
    const int w   = tid >> 6;          // wave 0..3
    const int l   = tid & 63;          // lane
    const int h   = l >> 5;            // half-wave
    const int q   = l & 31;            // this lane's query column (swapped QK^T)
    const int bid = blockIdx.x;
    const int b   = bid >> 5;          // batch 0..7
    const int qt  = bid & 31;          // q-tile 0..31
    const float* xb = x + (size_t)b * (N * C);
    const int qbase = qt * QB;

    // ---- Q fragments (B-operand of S^T = K·Q^T): Q[qrow][16*kk + 8*h + j] ----
    const int qrow = qbase + w * 32 + q;
    f16x8 Qf[4];
    {
        const float* qs = xb + (size_t)qrow * C + h * 8;
        #pragma unroll
        for (int kk = 0; kk < 4; ++kk) {
            f32x4 a = *(const f32x4*)(qs + kk * 16);
            f32x4 c2 = *(const f32x4*)(qs + kk * 16 + 4);
            f16x8 f;
            f[0] = (f16)a[0];  f[1] = (f16)a[1];  f[2] = (f16)a[2];  f[3] = (f16)a[3];
            f[4] = (f16)c2[0]; f[5] = (f16)c2[1]; f[6] = (f16)c2[2]; f[7] = (f16)c2[3];
            Qf[kk] = f;
        }
    }

    // ---- staging assignment: lane = channel c, wave = key group of 16 ----
    const int sc = l;      // channel 0..63
    const int sg = w;      // key group (16 keys each)
    float stg[16];

    auto stage_load = [&](int kt) {
        const float* src = xb + ((size_t)(kt * KV + sg * 16) * C + sc);
        #pragma unroll
        for (int j = 0; j < 16; ++j) stg[j] = src[j * C];   // coalesced dwords
    };
    auto stage_write = [&](int sel) {
        char* kb = (char*)smem + sel * 8192;           // K [key][c]
        char* vb = (char*)smem + 16384 + sel * 8192;   // V^T [c][key]
        #pragma unroll
        for (int j = 0; j < 16; ++j) {
            int row = sg * 16 + j;
            *(f16*)(kb + swz(row, sc * 2)) = (f16)stg[j];   // conflict-free b16
        }
        #pragma unroll
        for (int u = 0; u < 4; ++u) {
            f16x4 v4 = {(f16)stg[4*u], (f16)stg[4*u+1], (f16)stg[4*u+2], (f16)stg[4*u+3]};
            *(f16x4*)(vb + swz(sc, (sg * 16 + u * 4) * 2)) = v4;  // ~4-way b64
        }
    };

    f32x16 ot[2] = {};                 // O^T accum: row=c (2 tiles of 32), col=q
    float m_run = -INFINITY, l_run = 0.f;

    stage_load(0);
    stage_write(0);
    __syncthreads();

    int cur = 0;
    for (int kt = 0; kt < NT; ++kt) {
        if (kt + 1 < NT) stage_load(kt + 1);   // issue early (T14)

        const char* kb = (const char*)smem + cur * 8192;
        const char* vb = (const char*)smem + 16384 + cur * 8192;

        // ---- S^T = K · Q^T  (rows = keys, cols = queries) ----
        f32x16 st[2];
        #pragma unroll
        for (int n = 0; n < 2; ++n) {
            f32x16 acc = {};
            #pragma unroll
            for (int kk = 0; kk < 4; ++kk) {
                f16x8 kf = *(const f16x8*)(kb + swz(q + 32 * n, (kk * 16 + h * 8) * 2));
                acc = MFMA_F16(kf, Qf[kk], acc, 0, 0, 0);
            }
            st[n] = acc;
        }

        // ---- online softmax: lane owns query q; its 32 regs are 32 keys ----
        float pmax = -INFINITY;
        #pragma unroll
        for (int n = 0; n < 2; ++n)
            #pragma unroll
            for (int r2 = 0; r2 < 16; ++r2) pmax = fmaxf(pmax, st[n][r2]);
        pmax = fmaxf(pmax, __shfl_xor(pmax, 32, 64));
        float m_new = fmaxf(m_run, pmax);
        float scale = __expf(m_run - m_new);   // first iter: exp(-inf)=0
        float rs = 0.f;
        #pragma unroll
        for (int n = 0; n < 2; ++n)
            #pragma unroll
            for (int r2 = 0; r2 < 16; ++r2) {
                float p = __expf(st[n][r2] - m_new);
                st[n][r2] = p;
                rs += p;
            }
        rs += __shfl_xor(rs, 32, 64);
        l_run = l_run * scale + rs;
        m_run = m_new;
        #pragma unroll
        for (int mI = 0; mI < 2; ++mI)
            #pragma unroll
            for (int r2 = 0; r2 < 16; ++r2) ot[mI][r2] *= scale;

        // ---- P^T -> f16 B-fragments via pack + cross-half exchange ----
        // B-frag(kk) elem j: key = 16*kk + 8*h + j; held key = 32n + 8s + r + 4*h_src
        f16x8 Pf[4];
        #pragma unroll
        for (int kk = 0; kk < 4; ++kk) {
            int n  = kk >> 1;
            int so = 2 * (kk & 1) + h;         // s needed by me
            int sx = 2 * (kk & 1) + (1 - h);   // s needed by my partner lane
            f16x2 a0 = { (f16)st[n][so*4+0], (f16)st[n][so*4+1] };
            f16x2 a1 = { (f16)st[n][so*4+2], (f16)st[n][so*4+3] };
            f16x2 b0 = { (f16)st[n][sx*4+0], (f16)st[n][sx*4+1] };
            f16x2 b1 = { (f16)st[n][sx*4+2], (f16)st[n][sx*4+3] };
            u32 ua0 = __builtin_bit_cast(u32, a0), ua1 = __builtin_bit_cast(u32, a1);
            u32 ub0 = __builtin_bit_cast(u32, b0), ub1 = __builtin_bit_cast(u32, b1);
            u32 r0 = __shfl_xor(ub0, 32, 64);  // partner's pack for MY s
            u32 r1 = __shfl_xor(ub1, 32, 64);
            u32x4 uv;
            uv[0] = h ? r0 : ua0;   // j=0..3 always from h_src=0
            uv[1] = h ? r1 : ua1;
            uv[2] = h ? ua0 : r0;   // j=4..7 always from h_src=1
            uv[3] = h ? ua1 : r1;
            Pf[kk] = __builtin_bit_cast(f16x8, uv);
        }

        if (kt + 1 < NT) stage_write(cur ^ 1);  // loads have had S+softmax to land

        // ---- O^T += V^T · P^T ----
        #pragma unroll
        for (int mI = 0; mI < 2; ++mI) {
            f32x16 acc = ot[mI];
            #pragma unroll
            for (int kk = 0; kk < 4; ++kk) {
                f16x8 vf = *(const f16x8*)(vb + swz(q + 32 * mI, (kk * 16 + h * 8) * 2));
                acc = MFMA_F16(vf, Pf[kk], acc, 0, 0, 0);
            }
            ot[mI] = acc;
        }

        __syncthreads();
        cur ^= 1;
    }

    // ---- epilogue: O^T/l through padded LDS -> coalesced float4 out ----
    float* ep = (float*)smem + w * (64 * 33);
    float invl = 1.0f / l_run;
    #pragma unroll
    for (int mI = 0; mI < 2; ++mI)
        #pragma unroll
        for (int r2 = 0; r2 < 16; ++r2) {
            int c = 32 * mI + (r2 & 3) + 8 * (r2 >> 2) + 4 * h;
            ep[c * 33 + q] = ot[mI][r2] * invl;
        }
    __syncthreads();

    const float g = gamma[0];
    float* ob = out + (size_t)b * (N * C);
    #pragma unroll
    for (int it = 0; it < 8; ++it) {
        int ql = it * 4 + (l >> 4);
        int c0 = (l & 15) * 4;
        f32x4 o;
        o[0] = ep[(c0 + 0) * 33 + ql];
        o[1] = ep[(c0 + 1) * 33 + ql];
        o[2] = ep[(c0 + 2) * 33 + ql];
        o[3] = ep[(c0 + 3) * 33 + ql];
        int row = qbase + w * 32 + ql;
        f32x4 xi = *(const f32x4*)(xb + (size_t)row * C + c0);
        f32x4 res = { g * o[0] + xi[0], g * o[1] + xi[1],
                      g * o[2] + xi[2], g * o[3] + xi[3] };
        *(f32x4*)(ob + (size_t)row * C + c0) = res;
    }
}

extern "C" void kernel_launch(void* const* d_in, const int* in_sizes, int n_in,
                              void* d_out, int out_size, void* d_ws, size_t ws_size,
                              hipStream_t stream) {
    const float* x     = (const float*)d_in[0];
    const float* gamma = (const float*)d_in[1];
    float* out         = (float*)d_out;
    dim3 grid(256), block(256);
    channel_attn_kernel<<<grid, block, 0, stream>>>(x, gamma, out);
}

// Round 2
// 207.544 us; speedup vs baseline: 1.3755x; 1.3755x over previous
//
#include <hip/hip_runtime.h>

typedef _Float16 f16;
typedef _Float16 f16x8 __attribute__((ext_vector_type(8)));
typedef _Float16 f16x4 __attribute__((ext_vector_type(4)));
typedef _Float16 f16x2 __attribute__((ext_vector_type(2)));
typedef float f32x16 __attribute__((ext_vector_type(16)));
typedef float f32x4 __attribute__((ext_vector_type(4)));
typedef unsigned int u32;
typedef u32 u32x2 __attribute__((ext_vector_type(2)));
typedef u32 u32x4v __attribute__((ext_vector_type(4)));

#define MFMA_F16 __builtin_amdgcn_mfma_f32_32x32x16_f16

// x: (B=8, N=4096, C=64) fp32; out = gamma*softmax(qq^T)q + x
constexpr int N    = 4096;
constexpr int C    = 64;
constexpr int KV   = 64;          // keys per tile
constexpr int QB   = 128;         // queries per block
constexpr int NGRP = 2;           // KV-split groups
constexpr int NT2  = N / KV / NGRP;  // 32 tiles per group
constexpr float LOG2E = 1.44269504088896f;
constexpr float THR   = 11.0f;    // defer-max threshold (log2 units); P <= 2^11 ok in f16

__device__ __forceinline__ float fexp2(float x) {
#if __has_builtin(__builtin_amdgcn_exp2f)
    return __builtin_amdgcn_exp2f(x);
#else
    return __expf(x * 0.69314718055994531f);
#endif
}

__device__ __forceinline__ u32 pkrtz(float a, float b) {
    return __builtin_bit_cast(u32, __builtin_amdgcn_cvt_pkrtz(a, b));
}

// fine XOR swizzle: 8-byte granule spread across 16 slots of a 128-B row
__device__ __forceinline__ int swz8(int row, int bcol) {
    return row * 128 + (bcol ^ ((row & 15) << 3));
}

__device__ __forceinline__ f16x8 frag8(const char* base, int row, int bcol) {
    f16x4 lo = *(const f16x4*)(base + swz8(row, bcol));
    f16x4 hi = *(const f16x4*)(base + swz8(row, bcol + 8));
    return __builtin_shufflevector(lo, hi, 0, 1, 2, 3, 4, 5, 6, 7);
}

__global__ __launch_bounds__(512, 2)
void channel_attn_kernel(const float* __restrict__ x,
                         const float* __restrict__ gamma,
                         float* __restrict__ out) {
    // staging: 2 groups x 2 bufs x (K 8 KB + V^T 8 KB) = 64 KB
    // merge (reuse): pO [64][128] f32 @0 (32 KB), pm @32768, pl @33280,
    //                transpose ep @33792 + qw*8448 (4 waves) -> 67584 total
    __shared__ __align__(16) unsigned char smem[67584];

    const int tid = threadIdx.x;
    const int w   = tid >> 6;
    const int g   = w >> 2;           // kv group 0/1
    const int qw  = w & 3;            // query sub-tile within block
    const int l   = tid & 63;
    const int h   = l >> 5;
    const int q   = l & 31;
    const int bid = blockIdx.x;
    const int b   = bid >> 5;
    const int qt  = bid & 31;
    const float* xb = x + (size_t)b * (N * C);
    const int qbase = qt * QB;
    const int qg = qw * 32 + q;

    // ---- Q fragments, pre-scaled by log2(e) (exp2-domain softmax) ----
    const int qrow = qbase + qg;
    f16x8 Qf[4];
    {
        const float* qs = xb + (size_t)qrow * C + h * 8;
        #pragma unroll
        for (int kk = 0; kk < 4; ++kk) {
            f32x4 a  = *(const f32x4*)(qs + kk * 16);
            f32x4 c2 = *(const f32x4*)(qs + kk * 16 + 4);
            f16x8 f;
            f[0] = (f16)(a[0] * LOG2E);  f[1] = (f16)(a[1] * LOG2E);
            f[2] = (f16)(a[2] * LOG2E);  f[3] = (f16)(a[3] * LOG2E);
            f[4] = (f16)(c2[0] * LOG2E); f[5] = (f16)(c2[1] * LOG2E);
            f[6] = (f16)(c2[2] * LOG2E); f[7] = (f16)(c2[3] * LOG2E);
            Qf[kk] = f;
        }
    }

    // ---- staging: lane = channel, wave(qw) = 16-key group, per kv-group bufs ----
    const int sc = l;
    const int sg = qw;
    float stg[16];

    auto stage_load = [&](int kt) {
        const float* src = xb + ((size_t)((g * NT2 + kt) * KV + sg * 16) * C + sc);
        #pragma unroll
        for (int j = 0; j < 16; ++j) stg[j] = src[j * C];   // coalesced, imm offsets
    };
    auto stage_write = [&](int sel) {
        char* kb = (char*)smem + ((g << 1) | sel) * 16384;  // K [key][c] f16
        char* vb = kb + 8192;                               // V^T [c][key] f16
        #pragma unroll
        for (int j = 0; j < 16; ++j)
            *(f16*)(kb + swz8(sg * 16 + j, sc * 2)) = (f16)stg[j];
        #pragma unroll
        for (int u = 0; u < 4; ++u) {
            u32x2 vv = { pkrtz(stg[4*u+0], stg[4*u+1]), pkrtz(stg[4*u+2], stg[4*u+3]) };
            *(u32x2*)(vb + swz8(sc, (sg * 16 + u * 4) * 2)) = vv;   // bank-optimal b64
        }
    };

    f32x16 ot[2] = {};
    float m_run = -INFINITY, l_run = 0.f;

    stage_load(0);
    stage_write(0);
    __syncthreads();

    int cur = 0;
    for (int kt = 0; kt < NT2; ++kt) {
        if (kt + 1 < NT2) stage_load(kt + 1);      // issue early (T14)

        const char* kb = (const char*)smem + ((g << 1) | cur) * 16384;
        const char* vb = kb + 8192;

        // ---- S'^T = K · (log2e·Q)^T ----
        f32x16 st[2];
        #pragma unroll
        for (int n = 0; n < 2; ++n) {
            f32x16 acc = {};
            #pragma unroll
            for (int kk = 0; kk < 4; ++kk) {
                f16x8 kf = frag8(kb, q + 32 * n, (kk * 16 + h * 8) * 2);
                acc = MFMA_F16(kf, Qf[kk], acc, 0, 0, 0);
            }
            st[n] = acc;
        }

        // ---- online softmax (log2 domain), tree reduces ----
        float mx[4];
        #pragma unroll
        for (int t = 0; t < 4; ++t) mx[t] = fmaxf(st[0][t], st[1][t]);
        #pragma unroll
        for (int r2 = 4; r2 < 16; r2 += 4)
            #pragma unroll
            for (int t = 0; t < 4; ++t)
                mx[t] = fmaxf(mx[t], fmaxf(st[0][r2 + t], st[1][r2 + t]));
        float pmax = fmaxf(fmaxf(mx[0], mx[1]), fmaxf(mx[2], mx[3]));
        pmax = fmaxf(pmax, __shfl_xor(pmax, 32, 64));

        if (!__all(pmax - m_run <= THR)) {          // defer-max (T13)
            float m_new = fmaxf(m_run, pmax);
            float scf = fexp2(m_run - m_new);
            l_run *= scf;
            #pragma unroll
            for (int mI = 0; mI < 2; ++mI)
                #pragma unroll
                for (int r2 = 0; r2 < 16; ++r2) ot[mI][r2] *= scf;
            m_run = m_new;
        }

        float rs4[4] = {0.f, 0.f, 0.f, 0.f};
        #pragma unroll
        for (int n = 0; n < 2; ++n)
            #pragma unroll
            for (int r2 = 0; r2 < 16; ++r2) {
                float p = fexp2(st[n][r2] - m_run);
                st[n][r2] = p;
                rs4[r2 & 3] += p;
            }
        float rs = (rs4[0] + rs4[1]) + (rs4[2] + rs4[3]);
        rs += __shfl_xor(rs, 32, 64);
        l_run += rs;

        // ---- P^T -> f16 B-fragments (pkrtz + cross-half exchange) ----
        f16x8 Pf[4];
        #pragma unroll
        for (int kk = 0; kk < 4; ++kk) {
            int n  = kk >> 1;
            int so = 2 * (kk & 1) + h;
            int sx = 2 * (kk & 1) + (1 - h);
            u32 ua0 = pkrtz(st[n][so*4+0], st[n][so*4+1]);
            u32 ua1 = pkrtz(st[n][so*4+2], st[n][so*4+3]);
            u32 ub0 = pkrtz(st[n][sx*4+0], st[n][sx*4+1]);
            u32 ub1 = pkrtz(st[n][sx*4+2], st[n][sx*4+3]);
            u32 r0 = __shfl_xor(ub0, 32, 64);
            u32 r1 = __shfl_xor(ub1, 32, 64);
            u32x4v uv;
            uv[0] = h ? r0 : ua0;
            uv[1] = h ? r1 : ua1;
            uv[2] = h ? ua0 : r0;
            uv[3] = h ? ua1 : r1;
            Pf[kk] = __builtin_bit_cast(f16x8, uv);
        }

        if (kt + 1 < NT2) stage_write(cur ^ 1);

        // ---- O^T += V^T · P^T ----
        #pragma unroll
        for (int mI = 0; mI < 2; ++mI) {
            f32x16 acc = ot[mI];
            #pragma unroll
            for (int kk = 0; kk < 4; ++kk) {
                f16x8 vf = frag8(vb, q + 32 * mI, (kk * 16 + h * 8) * 2);
                acc = MFMA_F16(vf, Pf[kk], acc, 0, 0, 0);
            }
            ot[mI] = acc;
        }

        __syncthreads();
        cur ^= 1;
    }

    // ---- merge the two KV-group partials, then epilogue ----
    float* pO = (float*)smem;                   // [64][128]
    float* pm = (float*)(smem + 32768);         // [128]
    float* pl = (float*)(smem + 33280);         // [128]

    if (g == 1) {
        #pragma unroll
        for (int mI = 0; mI < 2; ++mI)
            #pragma unroll
            for (int r2 = 0; r2 < 16; ++r2) {
                int c = 32 * mI + (r2 & 3) + 8 * (r2 >> 2) + 4 * h;
                pO[c * 128 + qg] = ot[mI][r2];
            }
        if (h == 0) { pm[qg] = m_run; pl[qg] = l_run; }
    }
    __syncthreads();

    if (g == 0) {
        float m1 = pm[qg], l1 = pl[qg];
        float M  = fmaxf(m_run, m1);
        float a0 = fexp2(m_run - M);
        float a1 = fexp2(m1 - M);
        float invl = 1.0f / (l_run * a0 + l1 * a1);

        float* ep = (float*)(smem + 33792 + qw * 8448);   // [64][33] per wave
        #pragma unroll
        for (int mI = 0; mI < 2; ++mI)
            #pragma unroll
            for (int r2 = 0; r2 < 16; ++r2) {
                int c = 32 * mI + (r2 & 3) + 8 * (r2 >> 2) + 4 * h;
                float o = (ot[mI][r2] * a0 + pO[c * 128 + qg] * a1) * invl;
                ep[c * 33 + q] = o;
            }

        const float gm = gamma[0];
        float* ob = out + (size_t)b * (N * C);
        #pragma unroll
        for (int it = 0; it < 8; ++it) {
            int ql = it * 4 + (l >> 4);
            int c0 = (l & 15) * 4;
            f32x4 o;
            o[0] = ep[(c0 + 0) * 33 + ql];
            o[1] = ep[(c0 + 1) * 33 + ql];
            o[2] = ep[(c0 + 2) * 33 + ql];
            o[3] = ep[(c0 + 3) * 33 + ql];
            int row = qbase + qw * 32 + ql;
            f32x4 xi = *(const f32x4*)(xb + (size_t)row * C + c0);
            f32x4 res = { gm * o[0] + xi[0], gm * o[1] + xi[1],
                          gm * o[2] + xi[2], gm * o[3] + xi[3] };
            *(f32x4*)(ob + (size_t)row * C + c0) = res;
        }
    }
}

extern "C" void kernel_launch(void* const* d_in, const int* in_sizes, int n_in,
                              void* d_out, int out_size, void* d_ws, size_t ws_size,
                              hipStream_t stream) {
    const float* x     = (const float*)d_in[0];
    const float* gamma = (const float*)d_in[1];
    float* out         = (float*)d_out;
    dim3 grid(256), block(512);
    channel_attn_kernel<<<grid, block, 0, stream>>>(x, gamma, out);
}